// Round 1
// baseline (3747.486 us; speedup 1.0000x reference)
//
#include <hip/hip_runtime.h>

#define NN 50000
#define NE 800000

__device__ __forceinline__ float silu_f(float v) {
    return v / (1.0f + __expf(-v));
}

// ---------------------------------------------------------------------------
// Edge kernel: per 64-edge block
//   ein = [x[row] (128) | x[col] (128) | dij (1)]   (K = 257)
//   h1  = silu(ein @ We1 + be1)        [64 x 128]
//   m   = silu(h1  @ We2 + be2)        [64 x 128]
//   agg[row]   += m            (atomics)
//   w = silu(m @ Wc + bc); delta[row] += rij * w  (atomics)
// Thread layout: 256 threads = 16 (edge groups, ty) x 16 (col groups, tx),
// each thread owns a 4x8 register tile.
// ---------------------------------------------------------------------------
__global__ __launch_bounds__(256) void egnn_edge(
    const float* __restrict__ x, const float* __restrict__ pos,
    const float* __restrict__ We1, const float* __restrict__ be1,
    const float* __restrict__ We2, const float* __restrict__ be2,
    const float* __restrict__ Wc, const float* __restrict__ bc,
    const int* __restrict__ ei,
    float* __restrict__ agg, float* __restrict__ delta)
{
    __shared__ float A[64][36];     // K-tile of gathered edge inputs
    __shared__ float Bs[32][128];   // K-tile of weights
    __shared__ float Hs[64][132];   // h1 (after silu)
    __shared__ int   rows_s[64], cols_s[64];
    __shared__ float rij_s[64][3];
    __shared__ float dij_s[64];

    const int tid = threadIdx.x;
    const int ty = tid >> 4, tx = tid & 15;
    const int e0 = blockIdx.x * 64;
    const int j0 = tx * 8;

    if (tid < 64) {
        int r = ei[e0 + tid];
        int c = ei[NE + e0 + tid];
        rows_s[tid] = r; cols_s[tid] = c;
        float d = 0.f;
        #pragma unroll
        for (int k = 0; k < 3; ++k) {
            float rv = pos[r * 3 + k] - pos[c * 3 + k];
            rij_s[tid][k] = rv; d += rv * rv;
        }
        dij_s[tid] = d;
    }

    float acc[4][8];
    #pragma unroll
    for (int i = 0; i < 4; ++i)
        #pragma unroll
        for (int u = 0; u < 8; ++u) acc[i][u] = be1[j0 + u];

    // ---- layer 1: K = 256 (dij rank-1 term added after) ----
    for (int kt = 0; kt < 8; ++kt) {
        __syncthreads();
        {   // stage A: 64 edges x 32 k
            int e  = tid >> 2;
            int kk = (tid & 3) * 8;
            int nrow = (kt < 4) ? rows_s[e] : cols_s[e];
            const float4* s4 = (const float4*)(x + (size_t)nrow * 128 + (kt & 3) * 32 + kk);
            float4 v0 = s4[0], v1 = s4[1];
            *(float4*)&A[e][kk]     = v0;
            *(float4*)&A[e][kk + 4] = v1;
        }
        {   // stage B: We1[kt*32 .. kt*32+32)[128]
            int k = tid >> 3;
            int c = (tid & 7) * 16;
            const float4* s4 = (const float4*)(We1 + (size_t)(kt * 32 + k) * 128 + c);
            float4 v0 = s4[0], v1 = s4[1], v2 = s4[2], v3 = s4[3];
            *(float4*)&Bs[k][c]      = v0;
            *(float4*)&Bs[k][c + 4]  = v1;
            *(float4*)&Bs[k][c + 8]  = v2;
            *(float4*)&Bs[k][c + 12] = v3;
        }
        __syncthreads();
        #pragma unroll
        for (int k = 0; k < 32; k += 4) {
            float a[4][4];
            #pragma unroll
            for (int i = 0; i < 4; ++i) {
                float4 t = *(const float4*)&A[ty * 4 + i][k];
                a[i][0] = t.x; a[i][1] = t.y; a[i][2] = t.z; a[i][3] = t.w;
            }
            float b[4][8];
            #pragma unroll
            for (int kk = 0; kk < 4; ++kk) {
                float4 t0 = *(const float4*)&Bs[k + kk][j0];
                float4 t1 = *(const float4*)&Bs[k + kk][j0 + 4];
                b[kk][0] = t0.x; b[kk][1] = t0.y; b[kk][2] = t0.z; b[kk][3] = t0.w;
                b[kk][4] = t1.x; b[kk][5] = t1.y; b[kk][6] = t1.z; b[kk][7] = t1.w;
            }
            #pragma unroll
            for (int kk = 0; kk < 4; ++kk)
                #pragma unroll
                for (int i = 0; i < 4; ++i)
                    #pragma unroll
                    for (int u = 0; u < 8; ++u)
                        acc[i][u] = fmaf(a[i][kk], b[kk][u], acc[i][u]);
        }
    }

    // dij rank-1 term + silu -> Hs
    {
        float w256[8];
        #pragma unroll
        for (int u = 0; u < 8; ++u) w256[u] = We1[(size_t)256 * 128 + j0 + u];
        #pragma unroll
        for (int i = 0; i < 4; ++i) {
            int e = ty * 4 + i;
            float d = dij_s[e];
            #pragma unroll
            for (int u = 0; u < 8; ++u) {
                float v = acc[i][u] + d * w256[u];
                Hs[e][j0 + u] = silu_f(v);
            }
        }
    }

    // ---- layer 2: K = 128 ----
    float acc2[4][8];
    #pragma unroll
    for (int i = 0; i < 4; ++i)
        #pragma unroll
        for (int u = 0; u < 8; ++u) acc2[i][u] = be2[j0 + u];

    for (int kt = 0; kt < 4; ++kt) {
        __syncthreads();   // Hs writes visible; prev Bs reads done
        {
            int k = tid >> 3;
            int c = (tid & 7) * 16;
            const float4* s4 = (const float4*)(We2 + (size_t)(kt * 32 + k) * 128 + c);
            float4 v0 = s4[0], v1 = s4[1], v2 = s4[2], v3 = s4[3];
            *(float4*)&Bs[k][c]      = v0;
            *(float4*)&Bs[k][c + 4]  = v1;
            *(float4*)&Bs[k][c + 8]  = v2;
            *(float4*)&Bs[k][c + 12] = v3;
        }
        __syncthreads();
        #pragma unroll
        for (int k = 0; k < 32; k += 4) {
            float a[4][4];
            #pragma unroll
            for (int i = 0; i < 4; ++i) {
                float4 t = *(const float4*)&Hs[ty * 4 + i][kt * 32 + k];
                a[i][0] = t.x; a[i][1] = t.y; a[i][2] = t.z; a[i][3] = t.w;
            }
            float b[4][8];
            #pragma unroll
            for (int kk = 0; kk < 4; ++kk) {
                float4 t0 = *(const float4*)&Bs[k + kk][j0];
                float4 t1 = *(const float4*)&Bs[k + kk][j0 + 4];
                b[kk][0] = t0.x; b[kk][1] = t0.y; b[kk][2] = t0.z; b[kk][3] = t0.w;
                b[kk][4] = t1.x; b[kk][5] = t1.y; b[kk][6] = t1.z; b[kk][7] = t1.w;
            }
            #pragma unroll
            for (int kk = 0; kk < 4; ++kk)
                #pragma unroll
                for (int i = 0; i < 4; ++i)
                    #pragma unroll
                    for (int u = 0; u < 8; ++u)
                        acc2[i][u] = fmaf(a[i][kk], b[kk][u], acc2[i][u]);
        }
    }

    // m = silu(acc2); aggregate
    float m[4][8];
    #pragma unroll
    for (int i = 0; i < 4; ++i)
        #pragma unroll
        for (int u = 0; u < 8; ++u) m[i][u] = silu_f(acc2[i][u]);

    #pragma unroll
    for (int i = 0; i < 4; ++i) {
        int r = rows_s[ty * 4 + i];
        #pragma unroll
        for (int u = 0; u < 8; ++u)
            atomicAdd(&agg[(size_t)r * 128 + j0 + u], m[i][u]);
    }

    // w_ij = silu(m . Wc + bc); delta[row] += rij * w
    float wc[8];
    #pragma unroll
    for (int u = 0; u < 8; ++u) wc[u] = Wc[j0 + u];
    #pragma unroll
    for (int i = 0; i < 4; ++i) {
        float p = 0.f;
        #pragma unroll
        for (int u = 0; u < 8; ++u) p = fmaf(m[i][u], wc[u], p);
        #pragma unroll
        for (int off = 1; off < 16; off <<= 1) p += __shfl_xor(p, off);
        if (tx == 0) {
            int e = ty * 4 + i;
            float w = silu_f(p + bc[0]);
            int r = rows_s[e];
            atomicAdd(&delta[(size_t)r * 3 + 0], rij_s[e][0] * w);
            atomicAdd(&delta[(size_t)r * 3 + 1], rij_s[e][1] * w);
            atomicAdd(&delta[(size_t)r * 3 + 2], rij_s[e][2] * w);
        }
    }
}

// ---------------------------------------------------------------------------
// Node kernel: x_new = silu([x | agg] @ Wn1 + bn1) @ Wn2 + bn2 ; pos update
// ---------------------------------------------------------------------------
__global__ __launch_bounds__(256) void egnn_node(
    const float* __restrict__ x, const float* __restrict__ pos,
    const float* __restrict__ Wn1, const float* __restrict__ bn1,
    const float* __restrict__ Wn2, const float* __restrict__ bn2,
    const float* __restrict__ agg, const float* __restrict__ delta,
    float* __restrict__ out)
{
    __shared__ float A[64][36];
    __shared__ float Bs[32][128];
    __shared__ float Hs[64][132];

    const int tid = threadIdx.x;
    const int ty = tid >> 4, tx = tid & 15;
    const int n0 = blockIdx.x * 64;
    const int j0 = tx * 8;

    float acc[4][8];
    #pragma unroll
    for (int i = 0; i < 4; ++i)
        #pragma unroll
        for (int u = 0; u < 8; ++u) acc[i][u] = bn1[j0 + u];

    for (int kt = 0; kt < 8; ++kt) {
        __syncthreads();
        {   // stage A: 64 nodes x 32 k  (k<128 from x, else from agg)
            int e  = tid >> 2;
            int kk = (tid & 3) * 8;
            int node = n0 + e; if (node >= NN) node = NN - 1;  // clamped; stores guarded
            const float* base = (kt < 4) ? (x  + (size_t)node * 128 + (kt & 3) * 32)
                                         : (agg + (size_t)node * 128 + (kt & 3) * 32);
            float4 v0 = *(const float4*)(base + kk);
            float4 v1 = *(const float4*)(base + kk + 4);
            *(float4*)&A[e][kk]     = v0;
            *(float4*)&A[e][kk + 4] = v1;
        }
        {   // stage B from Wn1
            int k = tid >> 3;
            int c = (tid & 7) * 16;
            const float4* s4 = (const float4*)(Wn1 + (size_t)(kt * 32 + k) * 128 + c);
            float4 v0 = s4[0], v1 = s4[1], v2 = s4[2], v3 = s4[3];
            *(float4*)&Bs[k][c]      = v0;
            *(float4*)&Bs[k][c + 4]  = v1;
            *(float4*)&Bs[k][c + 8]  = v2;
            *(float4*)&Bs[k][c + 12] = v3;
        }
        __syncthreads();
        #pragma unroll
        for (int k = 0; k < 32; k += 4) {
            float a[4][4];
            #pragma unroll
            for (int i = 0; i < 4; ++i) {
                float4 t = *(const float4*)&A[ty * 4 + i][k];
                a[i][0] = t.x; a[i][1] = t.y; a[i][2] = t.z; a[i][3] = t.w;
            }
            float b[4][8];
            #pragma unroll
            for (int kk = 0; kk < 4; ++kk) {
                float4 t0 = *(const float4*)&Bs[k + kk][j0];
                float4 t1 = *(const float4*)&Bs[k + kk][j0 + 4];
                b[kk][0] = t0.x; b[kk][1] = t0.y; b[kk][2] = t0.z; b[kk][3] = t0.w;
                b[kk][4] = t1.x; b[kk][5] = t1.y; b[kk][6] = t1.z; b[kk][7] = t1.w;
            }
            #pragma unroll
            for (int kk = 0; kk < 4; ++kk)
                #pragma unroll
                for (int i = 0; i < 4; ++i)
                    #pragma unroll
                    for (int u = 0; u < 8; ++u)
                        acc[i][u] = fmaf(a[i][kk], b[kk][u], acc[i][u]);
        }
    }

    #pragma unroll
    for (int i = 0; i < 4; ++i) {
        int e = ty * 4 + i;
        #pragma unroll
        for (int u = 0; u < 8; ++u) Hs[e][j0 + u] = silu_f(acc[i][u]);
    }

    float acc2[4][8];
    #pragma unroll
    for (int i = 0; i < 4; ++i)
        #pragma unroll
        for (int u = 0; u < 8; ++u) acc2[i][u] = bn2[j0 + u];

    for (int kt = 0; kt < 4; ++kt) {
        __syncthreads();
        {
            int k = tid >> 3;
            int c = (tid & 7) * 16;
            const float4* s4 = (const float4*)(Wn2 + (size_t)(kt * 32 + k) * 128 + c);
            float4 v0 = s4[0], v1 = s4[1], v2 = s4[2], v3 = s4[3];
            *(float4*)&Bs[k][c]      = v0;
            *(float4*)&Bs[k][c + 4]  = v1;
            *(float4*)&Bs[k][c + 8]  = v2;
            *(float4*)&Bs[k][c + 12] = v3;
        }
        __syncthreads();
        #pragma unroll
        for (int k = 0; k < 32; k += 4) {
            float a[4][4];
            #pragma unroll
            for (int i = 0; i < 4; ++i) {
                float4 t = *(const float4*)&Hs[ty * 4 + i][kt * 32 + k];
                a[i][0] = t.x; a[i][1] = t.y; a[i][2] = t.z; a[i][3] = t.w;
            }
            float b[4][8];
            #pragma unroll
            for (int kk = 0; kk < 4; ++kk) {
                float4 t0 = *(const float4*)&Bs[k + kk][j0];
                float4 t1 = *(const float4*)&Bs[k + kk][j0 + 4];
                b[kk][0] = t0.x; b[kk][1] = t0.y; b[kk][2] = t0.z; b[kk][3] = t0.w;
                b[kk][4] = t1.x; b[kk][5] = t1.y; b[kk][6] = t1.z; b[kk][7] = t1.w;
            }
            #pragma unroll
            for (int kk = 0; kk < 4; ++kk)
                #pragma unroll
                for (int i = 0; i < 4; ++i)
                    #pragma unroll
                    for (int u = 0; u < 8; ++u)
                        acc2[i][u] = fmaf(a[i][kk], b[kk][u], acc2[i][u]);
        }
    }

    // store x_new (no activation on final layer)
    #pragma unroll
    for (int i = 0; i < 4; ++i) {
        int node = n0 + ty * 4 + i;
        if (node < NN) {
            float4 v0, v1;
            v0.x = acc2[i][0]; v0.y = acc2[i][1]; v0.z = acc2[i][2]; v0.w = acc2[i][3];
            v1.x = acc2[i][4]; v1.y = acc2[i][5]; v1.z = acc2[i][6]; v1.w = acc2[i][7];
            *(float4*)(out + (size_t)node * 128 + j0)     = v0;
            *(float4*)(out + (size_t)node * 128 + j0 + 4) = v1;
        }
    }

    // pos_new = pos + 0.01 * delta
    if (tid < 192) {
        int n = n0 + tid / 3, d = tid % 3;
        if (n < NN)
            out[(size_t)NN * 128 + (size_t)n * 3 + d] =
                pos[(size_t)n * 3 + d] + 0.01f * delta[(size_t)n * 3 + d];
    }
}

extern "C" void kernel_launch(void* const* d_in, const int* in_sizes, int n_in,
                              void* d_out, int out_size, void* d_ws, size_t ws_size,
                              hipStream_t stream)
{
    const float* x   = (const float*)d_in[0];
    const float* pos = (const float*)d_in[1];
    const float* We1 = (const float*)d_in[2];
    const float* be1 = (const float*)d_in[3];
    const float* We2 = (const float*)d_in[4];
    const float* be2 = (const float*)d_in[5];
    const float* Wn1 = (const float*)d_in[6];
    const float* bn1 = (const float*)d_in[7];
    const float* Wn2 = (const float*)d_in[8];
    const float* bn2 = (const float*)d_in[9];
    const float* Wc  = (const float*)d_in[10];
    const float* bc  = (const float*)d_in[11];
    const int*   ei  = (const int*)d_in[12];

    float* agg   = (float*)d_ws;
    float* delta = agg + (size_t)NN * 128;
    float* out   = (float*)d_out;

    // zero the accumulators every launch (harness does not re-poison between replays)
    hipMemsetAsync(d_ws, 0, ((size_t)NN * 128 + (size_t)NN * 3) * sizeof(float), stream);

    egnn_edge<<<NE / 64, 256, 0, stream>>>(x, pos, We1, be1, We2, be2, Wc, bc, ei, agg, delta);
    egnn_node<<<(NN + 63) / 64, 256, 0, stream>>>(x, pos, Wn1, bn1, Wn2, bn2, agg, delta, out);
}

// Round 2
// 1963.198 us; speedup vs baseline: 1.9089x; 1.9089x over previous
//
#include <hip/hip_runtime.h>
#include <stdint.h>

#define NN 50000
#define NE 800000

__device__ __forceinline__ float silu_f(float v) {
    return v / (1.0f + __expf(-v));
}

__device__ __forceinline__ unsigned int pack2bf(float a, float b) {
    unsigned int ua = __float_as_uint(a), ub = __float_as_uint(b);
    ua = (ua + 0x7fffu + ((ua >> 16) & 1u)) >> 16;
    ub = (ub + 0x7fffu + ((ub >> 16) & 1u)) >> 16;
    return ua | (ub << 16);
}

// ---------------------------------------------------------------------------
// CSR build: histogram -> scan -> scatter
// ---------------------------------------------------------------------------
__global__ __launch_bounds__(256) void egnn_hist(const int* __restrict__ ei,
                                                 int* __restrict__ cnt) {
    int e = blockIdx.x * 256 + threadIdx.x;
    if (e < NE) atomicAdd(&cnt[ei[e]], 1);
}

__global__ __launch_bounds__(1024) void egnn_scan(const int* __restrict__ cnt,
                                                  int* __restrict__ off,
                                                  int* __restrict__ cur) {
    __shared__ int part[1024];
    const int t = threadIdx.x;
    const int CH = (NN + 1023) / 1024;
    int lo = t * CH, hi = lo + CH; if (hi > NN) hi = NN; if (lo > NN) lo = NN;
    int s = 0;
    for (int i = lo; i < hi; ++i) s += cnt[i];
    part[t] = s;
    __syncthreads();
    for (int d = 1; d < 1024; d <<= 1) {
        int v = (t >= d) ? part[t - d] : 0;
        __syncthreads();
        part[t] += v;
        __syncthreads();
    }
    int base = (t == 0) ? 0 : part[t - 1];
    for (int i = lo; i < hi; ++i) {
        off[i] = base; cur[i] = base; base += cnt[i];
    }
    if (t == 1023) off[NN] = NE;
}

__global__ __launch_bounds__(256) void egnn_scatter(const int* __restrict__ ei,
                                                    int* __restrict__ cur,
                                                    int* __restrict__ elist) {
    int e = blockIdx.x * 256 + threadIdx.x;
    if (e < NE) {
        int p = atomicAdd(&cur[ei[e]], 1);
        elist[p] = e;
    }
}

// ---------------------------------------------------------------------------
// Edge kernel. MODE 0: atomic epilogue (fallback). MODE 1: materialize m/trans.
// Thread tile: 4 edges x 8 cols, cols split {tx*4..+3} and {tx*4+64..+3}
// (2-way LDS bank aliasing on Bs reads instead of 8-way).
// ---------------------------------------------------------------------------
template<int MODE>
__global__ __launch_bounds__(256) void egnn_edge(
    const float* __restrict__ x, const float* __restrict__ pos,
    const float* __restrict__ We1, const float* __restrict__ be1,
    const float* __restrict__ We2, const float* __restrict__ be2,
    const float* __restrict__ Wc, const float* __restrict__ bc,
    const int* __restrict__ ei,
    float* __restrict__ agg, float* __restrict__ delta,
    unsigned short* __restrict__ m_out, float* __restrict__ trans)
{
    __shared__ float A[64][36];
    __shared__ float Bs[32][128];
    __shared__ float Hs[64][132];
    __shared__ int   rows_s[64], cols_s[64];
    __shared__ float rij_s[64][3];
    __shared__ float dij_s[64];

    const int tid = threadIdx.x;
    const int ty = tid >> 4, tx = tid & 15;
    const int e0 = blockIdx.x * 64;
    const int j0a = tx * 4;
    const int j0b = j0a + 64;

    if (tid < 64) {
        int r = ei[e0 + tid];
        int c = ei[NE + e0 + tid];
        rows_s[tid] = r; cols_s[tid] = c;
        float d = 0.f;
        #pragma unroll
        for (int k = 0; k < 3; ++k) {
            float rv = pos[r * 3 + k] - pos[c * 3 + k];
            rij_s[tid][k] = rv; d += rv * rv;
        }
        dij_s[tid] = d;
    }

    float acc[4][8];
    #pragma unroll
    for (int i = 0; i < 4; ++i)
        #pragma unroll
        for (int u = 0; u < 8; ++u)
            acc[i][u] = (u < 4) ? be1[j0a + u] : be1[j0b + u - 4];

    // ---- layer 1: K = 256 (dij rank-1 term added after) ----
    for (int kt = 0; kt < 8; ++kt) {
        __syncthreads();
        {   // stage A: 64 edges x 32 k
            int e  = tid >> 2;
            int kk = (tid & 3) * 8;
            int nrow = (kt < 4) ? rows_s[e] : cols_s[e];
            const float4* s4 = (const float4*)(x + (size_t)nrow * 128 + (kt & 3) * 32 + kk);
            float4 v0 = s4[0], v1 = s4[1];
            *(float4*)&A[e][kk]     = v0;
            *(float4*)&A[e][kk + 4] = v1;
        }
        {   // stage B: We1[kt*32 .. +32)[128]
            int k = tid >> 3;
            int c = (tid & 7) * 16;
            const float4* s4 = (const float4*)(We1 + (size_t)(kt * 32 + k) * 128 + c);
            float4 v0 = s4[0], v1 = s4[1], v2 = s4[2], v3 = s4[3];
            *(float4*)&Bs[k][c]      = v0;
            *(float4*)&Bs[k][c + 4]  = v1;
            *(float4*)&Bs[k][c + 8]  = v2;
            *(float4*)&Bs[k][c + 12] = v3;
        }
        __syncthreads();
        #pragma unroll
        for (int k = 0; k < 32; k += 4) {
            float a[4][4];
            #pragma unroll
            for (int i = 0; i < 4; ++i) {
                float4 t = *(const float4*)&A[ty * 4 + i][k];
                a[i][0] = t.x; a[i][1] = t.y; a[i][2] = t.z; a[i][3] = t.w;
            }
            float b[4][8];
            #pragma unroll
            for (int kk = 0; kk < 4; ++kk) {
                float4 t0 = *(const float4*)&Bs[k + kk][j0a];
                float4 t1 = *(const float4*)&Bs[k + kk][j0b];
                b[kk][0] = t0.x; b[kk][1] = t0.y; b[kk][2] = t0.z; b[kk][3] = t0.w;
                b[kk][4] = t1.x; b[kk][5] = t1.y; b[kk][6] = t1.z; b[kk][7] = t1.w;
            }
            #pragma unroll
            for (int kk = 0; kk < 4; ++kk)
                #pragma unroll
                for (int i = 0; i < 4; ++i)
                    #pragma unroll
                    for (int u = 0; u < 8; ++u)
                        acc[i][u] = fmaf(a[i][kk], b[kk][u], acc[i][u]);
        }
    }

    // dij rank-1 term + silu -> Hs
    {
        float w256[8];
        #pragma unroll
        for (int u = 0; u < 8; ++u)
            w256[u] = We1[(size_t)256 * 128 + ((u < 4) ? j0a + u : j0b + u - 4)];
        #pragma unroll
        for (int i = 0; i < 4; ++i) {
            int e = ty * 4 + i;
            float d = dij_s[e];
            #pragma unroll
            for (int u = 0; u < 8; ++u) {
                float v = silu_f(acc[i][u] + d * w256[u]);
                Hs[e][(u < 4) ? j0a + u : j0b + u - 4] = v;
            }
        }
    }

    // ---- layer 2: K = 128 ----
    float acc2[4][8];
    #pragma unroll
    for (int i = 0; i < 4; ++i)
        #pragma unroll
        for (int u = 0; u < 8; ++u)
            acc2[i][u] = (u < 4) ? be2[j0a + u] : be2[j0b + u - 4];

    for (int kt = 0; kt < 4; ++kt) {
        __syncthreads();
        {
            int k = tid >> 3;
            int c = (tid & 7) * 16;
            const float4* s4 = (const float4*)(We2 + (size_t)(kt * 32 + k) * 128 + c);
            float4 v0 = s4[0], v1 = s4[1], v2 = s4[2], v3 = s4[3];
            *(float4*)&Bs[k][c]      = v0;
            *(float4*)&Bs[k][c + 4]  = v1;
            *(float4*)&Bs[k][c + 8]  = v2;
            *(float4*)&Bs[k][c + 12] = v3;
        }
        __syncthreads();
        #pragma unroll
        for (int k = 0; k < 32; k += 4) {
            float a[4][4];
            #pragma unroll
            for (int i = 0; i < 4; ++i) {
                float4 t = *(const float4*)&Hs[ty * 4 + i][kt * 32 + k];
                a[i][0] = t.x; a[i][1] = t.y; a[i][2] = t.z; a[i][3] = t.w;
            }
            float b[4][8];
            #pragma unroll
            for (int kk = 0; kk < 4; ++kk) {
                float4 t0 = *(const float4*)&Bs[k + kk][j0a];
                float4 t1 = *(const float4*)&Bs[k + kk][j0b];
                b[kk][0] = t0.x; b[kk][1] = t0.y; b[kk][2] = t0.z; b[kk][3] = t0.w;
                b[kk][4] = t1.x; b[kk][5] = t1.y; b[kk][6] = t1.z; b[kk][7] = t1.w;
            }
            #pragma unroll
            for (int kk = 0; kk < 4; ++kk)
                #pragma unroll
                for (int i = 0; i < 4; ++i)
                    #pragma unroll
                    for (int u = 0; u < 8; ++u)
                        acc2[i][u] = fmaf(a[i][kk], b[kk][u], acc2[i][u]);
        }
    }

    // m = silu(acc2)
    float m[4][8];
    #pragma unroll
    for (int i = 0; i < 4; ++i)
        #pragma unroll
        for (int u = 0; u < 8; ++u) m[i][u] = silu_f(acc2[i][u]);

    if (MODE == 1) {
        // materialize m as bf16 (coalesced), compute w -> trans
        #pragma unroll
        for (int i = 0; i < 4; ++i) {
            size_t e = (size_t)(e0 + ty * 4 + i);
            uint2 pa, pb;
            pa.x = pack2bf(m[i][0], m[i][1]);
            pa.y = pack2bf(m[i][2], m[i][3]);
            pb.x = pack2bf(m[i][4], m[i][5]);
            pb.y = pack2bf(m[i][6], m[i][7]);
            *(uint2*)(m_out + e * 128 + j0a) = pa;
            *(uint2*)(m_out + e * 128 + j0b) = pb;
        }
        float wc[8];
        #pragma unroll
        for (int u = 0; u < 8; ++u)
            wc[u] = Wc[(u < 4) ? j0a + u : j0b + u - 4];
        #pragma unroll
        for (int i = 0; i < 4; ++i) {
            float p = 0.f;
            #pragma unroll
            for (int u = 0; u < 8; ++u) p = fmaf(m[i][u], wc[u], p);
            #pragma unroll
            for (int off2 = 1; off2 < 16; off2 <<= 1) p += __shfl_xor(p, off2);
            if (tx == 0) {
                int e = ty * 4 + i;
                float w = silu_f(p + bc[0]);
                size_t ge = (size_t)(e0 + e);
                trans[ge * 3 + 0] = rij_s[e][0] * w;
                trans[ge * 3 + 1] = rij_s[e][1] * w;
                trans[ge * 3 + 2] = rij_s[e][2] * w;
            }
        }
    } else {
        #pragma unroll
        for (int i = 0; i < 4; ++i) {
            int r = rows_s[ty * 4 + i];
            #pragma unroll
            for (int u = 0; u < 8; ++u)
                atomicAdd(&agg[(size_t)r * 128 + ((u < 4) ? j0a + u : j0b + u - 4)], m[i][u]);
        }
        float wc[8];
        #pragma unroll
        for (int u = 0; u < 8; ++u)
            wc[u] = Wc[(u < 4) ? j0a + u : j0b + u - 4];
        #pragma unroll
        for (int i = 0; i < 4; ++i) {
            float p = 0.f;
            #pragma unroll
            for (int u = 0; u < 8; ++u) p = fmaf(m[i][u], wc[u], p);
            #pragma unroll
            for (int off2 = 1; off2 < 16; off2 <<= 1) p += __shfl_xor(p, off2);
            if (tx == 0) {
                int e = ty * 4 + i;
                float w = silu_f(p + bc[0]);
                int r = rows_s[e];
                atomicAdd(&delta[(size_t)r * 3 + 0], rij_s[e][0] * w);
                atomicAdd(&delta[(size_t)r * 3 + 1], rij_s[e][1] * w);
                atomicAdd(&delta[(size_t)r * 3 + 2], rij_s[e][2] * w);
            }
        }
    }
}

// ---------------------------------------------------------------------------
// Gather: one wave per node; sum m (bf16) and trans over CSR edge list.
// ---------------------------------------------------------------------------
__global__ __launch_bounds__(256) void egnn_gather(
    const unsigned short* __restrict__ m, const float* __restrict__ trans,
    const int* __restrict__ off, const int* __restrict__ elist,
    float* __restrict__ agg, float* __restrict__ delta)
{
    int n = (blockIdx.x * 256 + threadIdx.x) >> 6;
    int lane = threadIdx.x & 63;
    if (n >= NN) return;
    int s = off[n], eend = off[n + 1];
    float a0 = 0.f, a1 = 0.f, t = 0.f;
    for (int i = s; i < eend; ++i) {
        int e = elist[i];
        unsigned int u = *(const unsigned int*)(m + (size_t)e * 128 + lane * 2);
        a0 += __uint_as_float(u << 16);
        a1 += __uint_as_float(u & 0xffff0000u);
        if (lane < 3) t += trans[(size_t)e * 3 + lane];
    }
    float2 w; w.x = a0; w.y = a1;
    *(float2*)(agg + (size_t)n * 128 + lane * 2) = w;
    if (lane < 3) delta[(size_t)n * 3 + lane] = t;
}

// ---------------------------------------------------------------------------
// Node kernel: x_new = silu([x | agg] @ Wn1 + bn1) @ Wn2 + bn2 ; pos update
// ---------------------------------------------------------------------------
__global__ __launch_bounds__(256) void egnn_node(
    const float* __restrict__ x, const float* __restrict__ pos,
    const float* __restrict__ Wn1, const float* __restrict__ bn1,
    const float* __restrict__ Wn2, const float* __restrict__ bn2,
    const float* __restrict__ agg, const float* __restrict__ delta,
    float* __restrict__ out)
{
    __shared__ float A[64][36];
    __shared__ float Bs[32][128];
    __shared__ float Hs[64][132];

    const int tid = threadIdx.x;
    const int ty = tid >> 4, tx = tid & 15;
    const int n0 = blockIdx.x * 64;
    const int j0a = tx * 4;
    const int j0b = j0a + 64;

    float acc[4][8];
    #pragma unroll
    for (int i = 0; i < 4; ++i)
        #pragma unroll
        for (int u = 0; u < 8; ++u)
            acc[i][u] = (u < 4) ? bn1[j0a + u] : bn1[j0b + u - 4];

    for (int kt = 0; kt < 8; ++kt) {
        __syncthreads();
        {
            int e  = tid >> 2;
            int kk = (tid & 3) * 8;
            int node = n0 + e; if (node >= NN) node = NN - 1;
            const float* base = (kt < 4) ? (x   + (size_t)node * 128 + (kt & 3) * 32)
                                         : (agg + (size_t)node * 128 + (kt & 3) * 32);
            float4 v0 = *(const float4*)(base + kk);
            float4 v1 = *(const float4*)(base + kk + 4);
            *(float4*)&A[e][kk]     = v0;
            *(float4*)&A[e][kk + 4] = v1;
        }
        {
            int k = tid >> 3;
            int c = (tid & 7) * 16;
            const float4* s4 = (const float4*)(Wn1 + (size_t)(kt * 32 + k) * 128 + c);
            float4 v0 = s4[0], v1 = s4[1], v2 = s4[2], v3 = s4[3];
            *(float4*)&Bs[k][c]      = v0;
            *(float4*)&Bs[k][c + 4]  = v1;
            *(float4*)&Bs[k][c + 8]  = v2;
            *(float4*)&Bs[k][c + 12] = v3;
        }
        __syncthreads();
        #pragma unroll
        for (int k = 0; k < 32; k += 4) {
            float a[4][4];
            #pragma unroll
            for (int i = 0; i < 4; ++i) {
                float4 t = *(const float4*)&A[ty * 4 + i][k];
                a[i][0] = t.x; a[i][1] = t.y; a[i][2] = t.z; a[i][3] = t.w;
            }
            float b[4][8];
            #pragma unroll
            for (int kk = 0; kk < 4; ++kk) {
                float4 t0 = *(const float4*)&Bs[k + kk][j0a];
                float4 t1 = *(const float4*)&Bs[k + kk][j0b];
                b[kk][0] = t0.x; b[kk][1] = t0.y; b[kk][2] = t0.z; b[kk][3] = t0.w;
                b[kk][4] = t1.x; b[kk][5] = t1.y; b[kk][6] = t1.z; b[kk][7] = t1.w;
            }
            #pragma unroll
            for (int kk = 0; kk < 4; ++kk)
                #pragma unroll
                for (int i = 0; i < 4; ++i)
                    #pragma unroll
                    for (int u = 0; u < 8; ++u)
                        acc[i][u] = fmaf(a[i][kk], b[kk][u], acc[i][u]);
        }
    }

    #pragma unroll
    for (int i = 0; i < 4; ++i) {
        int e = ty * 4 + i;
        #pragma unroll
        for (int u = 0; u < 8; ++u)
            Hs[e][(u < 4) ? j0a + u : j0b + u - 4] = silu_f(acc[i][u]);
    }

    float acc2[4][8];
    #pragma unroll
    for (int i = 0; i < 4; ++i)
        #pragma unroll
        for (int u = 0; u < 8; ++u)
            acc2[i][u] = (u < 4) ? bn2[j0a + u] : bn2[j0b + u - 4];

    for (int kt = 0; kt < 4; ++kt) {
        __syncthreads();
        {
            int k = tid >> 3;
            int c = (tid & 7) * 16;
            const float4* s4 = (const float4*)(Wn2 + (size_t)(kt * 32 + k) * 128 + c);
            float4 v0 = s4[0], v1 = s4[1], v2 = s4[2], v3 = s4[3];
            *(float4*)&Bs[k][c]      = v0;
            *(float4*)&Bs[k][c + 4]  = v1;
            *(float4*)&Bs[k][c + 8]  = v2;
            *(float4*)&Bs[k][c + 12] = v3;
        }
        __syncthreads();
        #pragma unroll
        for (int k = 0; k < 32; k += 4) {
            float a[4][4];
            #pragma unroll
            for (int i = 0; i < 4; ++i) {
                float4 t = *(const float4*)&Hs[ty * 4 + i][kt * 32 + k];
                a[i][0] = t.x; a[i][1] = t.y; a[i][2] = t.z; a[i][3] = t.w;
            }
            float b[4][8];
            #pragma unroll
            for (int kk = 0; kk < 4; ++kk) {
                float4 t0 = *(const float4*)&Bs[k + kk][j0a];
                float4 t1 = *(const float4*)&Bs[k + kk][j0b];
                b[kk][0] = t0.x; b[kk][1] = t0.y; b[kk][2] = t0.z; b[kk][3] = t0.w;
                b[kk][4] = t1.x; b[kk][5] = t1.y; b[kk][6] = t1.z; b[kk][7] = t1.w;
            }
            #pragma unroll
            for (int kk = 0; kk < 4; ++kk)
                #pragma unroll
                for (int i = 0; i < 4; ++i)
                    #pragma unroll
                    for (int u = 0; u < 8; ++u)
                        acc2[i][u] = fmaf(a[i][kk], b[kk][u], acc2[i][u]);
        }
    }

    #pragma unroll
    for (int i = 0; i < 4; ++i) {
        int node = n0 + ty * 4 + i;
        if (node < NN) {
            float4 v0, v1;
            v0.x = acc2[i][0]; v0.y = acc2[i][1]; v0.z = acc2[i][2]; v0.w = acc2[i][3];
            v1.x = acc2[i][4]; v1.y = acc2[i][5]; v1.z = acc2[i][6]; v1.w = acc2[i][7];
            *(float4*)(out + (size_t)node * 128 + j0a) = v0;
            *(float4*)(out + (size_t)node * 128 + j0b) = v1;
        }
    }

    if (tid < 192) {
        int n = n0 + tid / 3, d = tid % 3;
        if (n < NN)
            out[(size_t)NN * 128 + (size_t)n * 3 + d] =
                pos[(size_t)n * 3 + d] + 0.01f * delta[(size_t)n * 3 + d];
    }
}

extern "C" void kernel_launch(void* const* d_in, const int* in_sizes, int n_in,
                              void* d_out, int out_size, void* d_ws, size_t ws_size,
                              hipStream_t stream)
{
    const float* x   = (const float*)d_in[0];
    const float* pos = (const float*)d_in[1];
    const float* We1 = (const float*)d_in[2];
    const float* be1 = (const float*)d_in[3];
    const float* We2 = (const float*)d_in[4];
    const float* be2 = (const float*)d_in[5];
    const float* Wn1 = (const float*)d_in[6];
    const float* bn1 = (const float*)d_in[7];
    const float* Wn2 = (const float*)d_in[8];
    const float* bn2 = (const float*)d_in[9];
    const float* Wc  = (const float*)d_in[10];
    const float* bc  = (const float*)d_in[11];
    const int*   ei  = (const int*)d_in[12];
    float* out = (float*)d_out;

    // ws layout (CSR path)
    const size_t SZ_M     = (size_t)NE * 128 * 2;           // 204,800,000
    const size_t SZ_TRANS = (size_t)NE * 3 * 4;             //   9,600,000
    const size_t SZ_AGG   = (size_t)NN * 128 * 4;           //  25,600,000
    const size_t SZ_DELTA = (size_t)NN * 3 * 4;             //     600,000
    const size_t SZ_CNT   = (size_t)NN * 4;
    const size_t SZ_OFF   = (size_t)(NN + 1) * 4;
    const size_t SZ_CUR   = (size_t)NN * 4;
    const size_t SZ_ELIST = (size_t)NE * 4;
    const size_t NEED = SZ_M + SZ_TRANS + SZ_AGG + SZ_DELTA + SZ_CNT + SZ_OFF + SZ_CUR + SZ_ELIST;

    if (ws_size >= NEED) {
        char* p = (char*)d_ws;
        unsigned short* m = (unsigned short*)p;  p += SZ_M;
        float* trans = (float*)p;                p += SZ_TRANS;
        float* agg   = (float*)p;                p += SZ_AGG;
        float* delta = (float*)p;                p += SZ_DELTA;
        int* cnt     = (int*)p;                  p += SZ_CNT;
        int* off     = (int*)p;                  p += SZ_OFF;
        int* cur     = (int*)p;                  p += SZ_CUR;
        int* elist   = (int*)p;

        hipMemsetAsync(cnt, 0, SZ_CNT, stream);
        egnn_hist<<<NE / 256, 256, 0, stream>>>(ei, cnt);
        egnn_scan<<<1, 1024, 0, stream>>>(cnt, off, cur);
        egnn_scatter<<<NE / 256, 256, 0, stream>>>(ei, cur, elist);
        egnn_edge<1><<<NE / 64, 256, 0, stream>>>(x, pos, We1, be1, We2, be2, Wc, bc, ei,
                                                  nullptr, nullptr, m, trans);
        egnn_gather<<<(NN * 64 + 255) / 256, 256, 0, stream>>>(m, trans, off, elist, agg, delta);
        egnn_node<<<(NN + 63) / 64, 256, 0, stream>>>(x, pos, Wn1, bn1, Wn2, bn2, agg, delta, out);
    } else {
        // fallback: atomic path (R1)
        float* agg   = (float*)d_ws;
        float* delta = agg + (size_t)NN * 128;
        hipMemsetAsync(d_ws, 0, ((size_t)NN * 128 + (size_t)NN * 3) * sizeof(float), stream);
        egnn_edge<0><<<NE / 64, 256, 0, stream>>>(x, pos, We1, be1, We2, be2, Wc, bc, ei,
                                                  agg, delta, nullptr, nullptr);
        egnn_node<<<(NN + 63) / 64, 256, 0, stream>>>(x, pos, Wn1, bn1, Wn2, bn2, agg, delta, out);
    }
}

// Round 3
// 871.986 us; speedup vs baseline: 4.2976x; 2.2514x over previous
//
#include <hip/hip_runtime.h>
#include <stdint.h>

#define NN 50000
#define NE 800000

typedef short bf8_t __attribute__((ext_vector_type(8)));
typedef float f32x4 __attribute__((ext_vector_type(4)));

__device__ __forceinline__ float silu_f(float v) { return v / (1.0f + __expf(-v)); }

__device__ __forceinline__ unsigned int pack2bf(float a, float b) {
    unsigned int ua = __float_as_uint(a), ub = __float_as_uint(b);
    ua = (ua + 0x7fffu + ((ua >> 16) & 1u)) >> 16;
    ub = (ub + 0x7fffu + ((ub >> 16) & 1u)) >> 16;
    return ua | (ub << 16);
}

union U4B { uint4 u; bf8_t b; };
__device__ __forceinline__ bf8_t as_bf8(uint4 u) { U4B x; x.u = u; return x.b; }

// ---------------------------------------------------------------------------
// prep: x f32 -> bf16 (xbf overlays the agg region; consumed before gather)
// ---------------------------------------------------------------------------
__global__ __launch_bounds__(256) void prep_x(const float* __restrict__ x,
                                              unsigned short* __restrict__ xbf) {
    size_t i = (size_t)blockIdx.x * 256 + threadIdx.x;   // 800000 threads x 8 elems
    const float4* s = (const float4*)(x + i * 8);
    float4 v0 = s[0], v1 = s[1];
    uint4 o;
    o.x = pack2bf(v0.x, v0.y); o.y = pack2bf(v0.z, v0.w);
    o.z = pack2bf(v1.x, v1.y); o.w = pack2bf(v1.z, v1.w);
    *(uint4*)(xbf + i * 8) = o;
}

// ---------------------------------------------------------------------------
// prep: weight fragments in MFMA A-operand order (W^T), bf16.
// frag f = s*8 + mf: lane holds W[k = s*32 + (lane>>4)*8 + i][col = mf*16 + (lane&15)]
// ---------------------------------------------------------------------------
__global__ __launch_bounds__(64) void prep_w(const float* __restrict__ We1,
                                             const float* __restrict__ We2,
                                             unsigned short* __restrict__ wf1,
                                             unsigned short* __restrict__ wf2) {
    int b = blockIdx.x, lane = threadIdx.x;
    int q = lane >> 4, c = lane & 15;
    const float* W; unsigned short* dst; int s, mf;
    if (b < 64) { W = We1; s = b >> 3; mf = b & 7; dst = wf1 + (size_t)b * 512; }
    else        { W = We2; int b2 = b - 64; s = b2 >> 3; mf = b2 & 7; dst = wf2 + (size_t)b2 * 512; }
    int k0 = s * 32 + q * 8, col = mf * 16 + c;
    float v[8];
    #pragma unroll
    for (int i = 0; i < 8; ++i) v[i] = W[(size_t)(k0 + i) * 128 + col];
    uint4 o;
    o.x = pack2bf(v[0], v[1]); o.y = pack2bf(v[2], v[3]);
    o.z = pack2bf(v[4], v[5]); o.w = pack2bf(v[6], v[7]);
    *(uint4*)(dst + lane * 8) = o;
}

// ---------------------------------------------------------------------------
// CSR build
// ---------------------------------------------------------------------------
__global__ __launch_bounds__(256) void egnn_hist(const int* __restrict__ ei,
                                                 int* __restrict__ cnt) {
    int e = blockIdx.x * 256 + threadIdx.x;
    if (e < NE) atomicAdd(&cnt[ei[e]], 1);
}

__global__ __launch_bounds__(1024) void egnn_scan(const int* __restrict__ cnt,
                                                  int* __restrict__ off,
                                                  int* __restrict__ cur) {
    __shared__ int part[1024];
    const int t = threadIdx.x;
    const int CH = (NN + 1023) / 1024;
    int lo = t * CH, hi = lo + CH; if (hi > NN) hi = NN; if (lo > NN) lo = NN;
    int s = 0;
    for (int i = lo; i < hi; ++i) s += cnt[i];
    part[t] = s;
    __syncthreads();
    for (int d = 1; d < 1024; d <<= 1) {
        int v = (t >= d) ? part[t - d] : 0;
        __syncthreads();
        part[t] += v;
        __syncthreads();
    }
    int base = (t == 0) ? 0 : part[t - 1];
    for (int i = lo; i < hi; ++i) { off[i] = base; cur[i] = base; base += cnt[i]; }
    if (t == 1023) off[NN] = NE;
}

__global__ __launch_bounds__(256) void egnn_scatter(const int* __restrict__ ei,
                                                    int* __restrict__ cur,
                                                    int* __restrict__ elist) {
    int e = blockIdx.x * 256 + threadIdx.x;
    if (e < NE) { int p = atomicAdd(&cur[ei[e]], 1); elist[p] = e; }
}

// ---------------------------------------------------------------------------
// Edge MFMA kernel. Block = 128 edges, 512 threads = 8 waves (P=4 col-quarters
// x Q=2 edge-halves). Swapped GEMM: D[out_col][edge] = W^T @ ein^T.
// A (weights) from LDS-staged fragment buffers; B (edge rows) gathered
// directly from global xbf (16 B/lane). h1 via padded LDS tile.
// ---------------------------------------------------------------------------
__global__ __launch_bounds__(512) void egnn_edge_mfma(
    const unsigned short* __restrict__ xbf, const float* __restrict__ pos,
    const unsigned short* __restrict__ wf1, const unsigned short* __restrict__ wf2,
    const float* __restrict__ We1, const float* __restrict__ be1,
    const float* __restrict__ be2,
    const int* __restrict__ ei, unsigned short* __restrict__ m_out)
{
    __shared__ unsigned short wb1[32768];      // 64 KB : We1^T frags (8 ksteps x 8 mf)
    __shared__ unsigned short wb2[16384];      // 32 KB : We2^T frags (4 ksteps x 8 mf)
    __shared__ unsigned short Hs[128 * 136];   // 34.8 KB : h1, padded stride 136
    __shared__ int rows_s[128], cols_s[128];
    __shared__ float dij_s[128];

    const int tid = threadIdx.x;
    const int e0 = blockIdx.x * 128;

    {   // stage weight frags (linear, coalesced)
        uint4* d1 = (uint4*)wb1; const uint4* s1 = (const uint4*)wf1;
        for (int i = tid; i < 4096; i += 512) d1[i] = s1[i];
        uint4* d2 = (uint4*)wb2; const uint4* s2 = (const uint4*)wf2;
        for (int i = tid; i < 2048; i += 512) d2[i] = s2[i];
    }
    if (tid < 128) {
        int r = ei[e0 + tid], c = ei[NE + e0 + tid];
        rows_s[tid] = r; cols_s[tid] = c;
        float d = 0.f;
        #pragma unroll
        for (int k = 0; k < 3; ++k) { float rv = pos[r * 3 + k] - pos[c * 3 + k]; d += rv * rv; }
        dij_s[tid] = d;
    }
    __syncthreads();

    const int w = tid >> 6, lane = tid & 63;
    const int P = w & 3, Q = w >> 2;
    const int q = lane >> 4, e16 = lane & 15;
    const int oc_q = P * 32 + q * 4;           // + M*16 per m-frag

    const unsigned short* rb[4]; const unsigned short* cb[4]; int eloc[4];
    #pragma unroll
    for (int t = 0; t < 4; ++t) {
        int el = Q * 64 + t * 16 + e16; eloc[t] = el;
        rb[t] = xbf + (size_t)rows_s[el] * 128;
        cb[t] = xbf + (size_t)cols_s[el] * 128;
    }

    // ---- layer 1: K=256 via MFMA, dij rank-1 + bias as f32 fixup ----
    f32x4 acc[2][4];
    #pragma unroll
    for (int M = 0; M < 2; ++M) {
        float4 bi = *(const float4*)(be1 + oc_q + M * 16);
        #pragma unroll
        for (int t = 0; t < 4; ++t) { acc[M][t][0] = bi.x; acc[M][t][1] = bi.y; acc[M][t][2] = bi.z; acc[M][t][3] = bi.w; }
    }

    #pragma unroll
    for (int s = 0; s < 8; ++s) {
        bf8_t bfr[4];
        #pragma unroll
        for (int t = 0; t < 4; ++t) {
            const unsigned short* base = (s < 4) ? rb[t] : cb[t];
            bfr[t] = as_bf8(*(const uint4*)(base + (s & 3) * 32 + q * 8));
        }
        #pragma unroll
        for (int M = 0; M < 2; ++M) {
            bf8_t af = as_bf8(*(const uint4*)(wb1 + (size_t)(s * 8 + P * 2 + M) * 512 + lane * 8));
            #pragma unroll
            for (int t = 0; t < 4; ++t)
                acc[M][t] = __builtin_amdgcn_mfma_f32_16x16x32_bf16(af, bfr[t], acc[M][t], 0, 0, 0);
        }
    }

    #pragma unroll
    for (int M = 0; M < 2; ++M) {
        float4 w256 = *(const float4*)(We1 + (size_t)256 * 128 + oc_q + M * 16);
        #pragma unroll
        for (int t = 0; t < 4; ++t) {
            float d = dij_s[eloc[t]];
            float v0 = silu_f(acc[M][t][0] + d * w256.x);
            float v1 = silu_f(acc[M][t][1] + d * w256.y);
            float v2 = silu_f(acc[M][t][2] + d * w256.z);
            float v3 = silu_f(acc[M][t][3] + d * w256.w);
            uint2 pk; pk.x = pack2bf(v0, v1); pk.y = pack2bf(v2, v3);
            *(uint2*)(Hs + (size_t)eloc[t] * 136 + oc_q + M * 16) = pk;
        }
    }
    __syncthreads();

    // ---- layer 2: K=128 ----
    f32x4 acc2[2][4];
    #pragma unroll
    for (int M = 0; M < 2; ++M) {
        float4 bi = *(const float4*)(be2 + oc_q + M * 16);
        #pragma unroll
        for (int t = 0; t < 4; ++t) { acc2[M][t][0] = bi.x; acc2[M][t][1] = bi.y; acc2[M][t][2] = bi.z; acc2[M][t][3] = bi.w; }
    }

    #pragma unroll
    for (int s = 0; s < 4; ++s) {
        bf8_t bfr[4];
        #pragma unroll
        for (int t = 0; t < 4; ++t)
            bfr[t] = as_bf8(*(const uint4*)(Hs + (size_t)eloc[t] * 136 + s * 32 + q * 8));
        #pragma unroll
        for (int M = 0; M < 2; ++M) {
            bf8_t af = as_bf8(*(const uint4*)(wb2 + (size_t)(s * 8 + P * 2 + M) * 512 + lane * 8));
            #pragma unroll
            for (int t = 0; t < 4; ++t)
                acc2[M][t] = __builtin_amdgcn_mfma_f32_16x16x32_bf16(af, bfr[t], acc2[M][t], 0, 0, 0);
        }
    }

    // ---- epilogue: m = silu(.) -> global bf16 ----
    #pragma unroll
    for (int M = 0; M < 2; ++M) {
        #pragma unroll
        for (int t = 0; t < 4; ++t) {
            float v0 = silu_f(acc2[M][t][0]);
            float v1 = silu_f(acc2[M][t][1]);
            float v2 = silu_f(acc2[M][t][2]);
            float v3 = silu_f(acc2[M][t][3]);
            uint2 pk; pk.x = pack2bf(v0, v1); pk.y = pack2bf(v2, v3);
            *(uint2*)(m_out + (size_t)(e0 + eloc[t]) * 128 + oc_q + M * 16) = pk;
        }
    }
}

// ---------------------------------------------------------------------------
// Gather: one wave per node; sums m (bf16) into agg, and computes the
// w_ij = silu(m.Wc + bc) dot + delta here (deletes the trans buffer).
// ---------------------------------------------------------------------------
__global__ __launch_bounds__(256) void egnn_gather(
    const unsigned short* __restrict__ m, const int* __restrict__ off,
    const int* __restrict__ elist, const int* __restrict__ ei,
    const float* __restrict__ pos, const float* __restrict__ Wc,
    const float* __restrict__ bc,
    float* __restrict__ agg, float* __restrict__ delta)
{
    int n = (blockIdx.x * 256 + threadIdx.x) >> 6;
    int lane = threadIdx.x & 63;
    if (n >= NN) return;
    float wc0 = Wc[lane * 2], wc1 = Wc[lane * 2 + 1];
    float bcs = bc[0];
    float pn = (lane < 3) ? pos[(size_t)n * 3 + lane] : 0.f;
    const unsigned int* m32 = (const unsigned int*)m;
    int s = off[n], e_end = off[n + 1];
    float a0 = 0.f, a1 = 0.f, td = 0.f;
    for (int i = s; i < e_end; ++i) {
        int e = elist[i];
        unsigned int u = m32[(size_t)e * 64 + lane];
        float lo = __uint_as_float(u << 16);
        float hi = __uint_as_float(u & 0xffff0000u);
        a0 += lo; a1 += hi;
        float dt = lo * wc0 + hi * wc1;
        #pragma unroll
        for (int o = 32; o; o >>= 1) dt += __shfl_xor(dt, o);
        float wgt = silu_f(dt + bcs);
        int cidx = ei[NE + e];
        if (lane < 3) td += (pn - pos[(size_t)cidx * 3 + lane]) * wgt;
    }
    float2 st; st.x = a0; st.y = a1;
    *(float2*)(agg + (size_t)n * 128 + lane * 2) = st;
    if (lane < 3) delta[(size_t)n * 3 + lane] = td;
}

// ---------------------------------------------------------------------------
// Node kernel (f32, unchanged from R2)
// ---------------------------------------------------------------------------
__global__ __launch_bounds__(256) void egnn_node(
    const float* __restrict__ x, const float* __restrict__ pos,
    const float* __restrict__ Wn1, const float* __restrict__ bn1,
    const float* __restrict__ Wn2, const float* __restrict__ bn2,
    const float* __restrict__ agg, const float* __restrict__ delta,
    float* __restrict__ out)
{
    __shared__ float A[64][36];
    __shared__ float Bs[32][128];
    __shared__ float Hs[64][132];

    const int tid = threadIdx.x;
    const int ty = tid >> 4, tx = tid & 15;
    const int n0 = blockIdx.x * 64;
    const int j0a = tx * 4;
    const int j0b = j0a + 64;

    float acc[4][8];
    #pragma unroll
    for (int i = 0; i < 4; ++i)
        #pragma unroll
        for (int u = 0; u < 8; ++u)
            acc[i][u] = (u < 4) ? bn1[j0a + u] : bn1[j0b + u - 4];

    for (int kt = 0; kt < 8; ++kt) {
        __syncthreads();
        {
            int e  = tid >> 2;
            int kk = (tid & 3) * 8;
            int node = n0 + e; if (node >= NN) node = NN - 1;
            const float* base = (kt < 4) ? (x   + (size_t)node * 128 + (kt & 3) * 32)
                                         : (agg + (size_t)node * 128 + (kt & 3) * 32);
            float4 v0 = *(const float4*)(base + kk);
            float4 v1 = *(const float4*)(base + kk + 4);
            *(float4*)&A[e][kk]     = v0;
            *(float4*)&A[e][kk + 4] = v1;
        }
        {
            int k = tid >> 3;
            int c = (tid & 7) * 16;
            const float4* s4 = (const float4*)(Wn1 + (size_t)(kt * 32 + k) * 128 + c);
            float4 v0 = s4[0], v1 = s4[1], v2 = s4[2], v3 = s4[3];
            *(float4*)&Bs[k][c]      = v0;
            *(float4*)&Bs[k][c + 4]  = v1;
            *(float4*)&Bs[k][c + 8]  = v2;
            *(float4*)&Bs[k][c + 12] = v3;
        }
        __syncthreads();
        #pragma unroll
        for (int k = 0; k < 32; k += 4) {
            float a[4][4];
            #pragma unroll
            for (int i = 0; i < 4; ++i) {
                float4 t = *(const float4*)&A[ty * 4 + i][k];
                a[i][0] = t.x; a[i][1] = t.y; a[i][2] = t.z; a[i][3] = t.w;
            }
            float b[4][8];
            #pragma unroll
            for (int kk = 0; kk < 4; ++kk) {
                float4 t0 = *(const float4*)&Bs[k + kk][j0a];
                float4 t1 = *(const float4*)&Bs[k + kk][j0b];
                b[kk][0] = t0.x; b[kk][1] = t0.y; b[kk][2] = t0.z; b[kk][3] = t0.w;
                b[kk][4] = t1.x; b[kk][5] = t1.y; b[kk][6] = t1.z; b[kk][7] = t1.w;
            }
            #pragma unroll
            for (int kk = 0; kk < 4; ++kk)
                #pragma unroll
                for (int i = 0; i < 4; ++i)
                    #pragma unroll
                    for (int u = 0; u < 8; ++u)
                        acc[i][u] = fmaf(a[i][kk], b[kk][u], acc[i][u]);
        }
    }

    #pragma unroll
    for (int i = 0; i < 4; ++i) {
        int e = ty * 4 + i;
        #pragma unroll
        for (int u = 0; u < 8; ++u)
            Hs[e][(u < 4) ? j0a + u : j0b + u - 4] = silu_f(acc[i][u]);
    }

    float acc2[4][8];
    #pragma unroll
    for (int i = 0; i < 4; ++i)
        #pragma unroll
        for (int u = 0; u < 8; ++u)
            acc2[i][u] = (u < 4) ? bn2[j0a + u] : bn2[j0b + u - 4];

    for (int kt = 0; kt < 4; ++kt) {
        __syncthreads();
        {
            int k = tid >> 3;
            int c = (tid & 7) * 16;
            const float4* s4 = (const float4*)(Wn2 + (size_t)(kt * 32 + k) * 128 + c);
            float4 v0 = s4[0], v1 = s4[1], v2 = s4[2], v3 = s4[3];
            *(float4*)&Bs[k][c]      = v0;
            *(float4*)&Bs[k][c + 4]  = v1;
            *(float4*)&Bs[k][c + 8]  = v2;
            *(float4*)&Bs[k][c + 12] = v3;
        }
        __syncthreads();
        #pragma unroll
        for (int k = 0; k < 32; k += 4) {
            float a[4][4];
            #pragma unroll
            for (int i = 0; i < 4; ++i) {
                float4 t = *(const float4*)&Hs[ty * 4 + i][kt * 32 + k];
                a[i][0] = t.x; a[i][1] = t.y; a[i][2] = t.z; a[i][3] = t.w;
            }
            float b[4][8];
            #pragma unroll
            for (int kk = 0; kk < 4; ++kk) {
                float4 t0 = *(const float4*)&Bs[k + kk][j0a];
                float4 t1 = *(const float4*)&Bs[k + kk][j0b];
                b[kk][0] = t0.x; b[kk][1] = t0.y; b[kk][2] = t0.z; b[kk][3] = t0.w;
                b[kk][4] = t1.x; b[kk][5] = t1.y; b[kk][6] = t1.z; b[kk][7] = t1.w;
            }
            #pragma unroll
            for (int kk = 0; kk < 4; ++kk)
                #pragma unroll
                for (int i = 0; i < 4; ++i)
                    #pragma unroll
                    for (int u = 0; u < 8; ++u)
                        acc2[i][u] = fmaf(a[i][kk], b[kk][u], acc2[i][u]);
        }
    }

    #pragma unroll
    for (int i = 0; i < 4; ++i) {
        int node = n0 + ty * 4 + i;
        if (node < NN) {
            float4 v0, v1;
            v0.x = acc2[i][0]; v0.y = acc2[i][1]; v0.z = acc2[i][2]; v0.w = acc2[i][3];
            v1.x = acc2[i][4]; v1.y = acc2[i][5]; v1.z = acc2[i][6]; v1.w = acc2[i][7];
            *(float4*)(out + (size_t)node * 128 + j0a) = v0;
            *(float4*)(out + (size_t)node * 128 + j0b) = v1;
        }
    }

    if (tid < 192) {
        int n = n0 + tid / 3, d = tid % 3;
        if (n < NN)
            out[(size_t)NN * 128 + (size_t)n * 3 + d] =
                pos[(size_t)n * 3 + d] + 0.01f * delta[(size_t)n * 3 + d];
    }
}

extern "C" void kernel_launch(void* const* d_in, const int* in_sizes, int n_in,
                              void* d_out, int out_size, void* d_ws, size_t ws_size,
                              hipStream_t stream)
{
    const float* x   = (const float*)d_in[0];
    const float* pos = (const float*)d_in[1];
    const float* We1 = (const float*)d_in[2];
    const float* be1 = (const float*)d_in[3];
    const float* We2 = (const float*)d_in[4];
    const float* be2 = (const float*)d_in[5];
    const float* Wn1 = (const float*)d_in[6];
    const float* bn1 = (const float*)d_in[7];
    const float* Wn2 = (const float*)d_in[8];
    const float* bn2 = (const float*)d_in[9];
    const float* Wc  = (const float*)d_in[10];
    const float* bc  = (const float*)d_in[11];
    const int*   ei  = (const int*)d_in[12];
    float* out = (float*)d_out;

    // ws layout (~235 MB; R2 proved ws >= 244 MB)
    char* p = (char*)d_ws;
    unsigned short* m = (unsigned short*)p;  p += (size_t)NE * 128 * 2;   // 204.8 MB
    float* agg   = (float*)p;                p += (size_t)NN * 128 * 4;   // 25.6 MB (also hosts xbf)
    float* delta = (float*)p;                p += (size_t)NN * 3 * 4;
    unsigned short* wf1 = (unsigned short*)p; p += 65536;
    unsigned short* wf2 = (unsigned short*)p; p += 32768;
    int* cnt   = (int*)p;                    p += (size_t)NN * 4;
    int* off   = (int*)p;                    p += (size_t)(NN + 1) * 4 + 12;  // pad to 16
    int* cur   = (int*)p;                    p += (size_t)NN * 4;
    int* elist = (int*)p;

    // xbf overlays agg: consumed by edge kernel, then gather rewrites agg fully.
    unsigned short* xbf = (unsigned short*)agg;

    hipMemsetAsync(cnt, 0, (size_t)NN * 4, stream);
    prep_x<<<3125, 256, 0, stream>>>(x, xbf);
    prep_w<<<96, 64, 0, stream>>>(We1, We2, wf1, wf2);
    egnn_hist<<<NE / 256, 256, 0, stream>>>(ei, cnt);
    egnn_scan<<<1, 1024, 0, stream>>>(cnt, off, cur);
    egnn_scatter<<<NE / 256, 256, 0, stream>>>(ei, cur, elist);
    egnn_edge_mfma<<<NE / 128, 512, 0, stream>>>(xbf, pos, wf1, wf2, We1, be1, be2, ei, m);
    egnn_gather<<<(NN * 64 + 255) / 256, 256, 0, stream>>>(m, off, elist, ei, pos, Wc, bc, agg, delta);
    egnn_node<<<(NN + 63) / 64, 256, 0, stream>>>(x, pos, Wn1, bn1, Wn2, bn2, agg, delta, out);
}

// Round 4
// 545.804 us; speedup vs baseline: 6.8660x; 1.5976x over previous
//
#include <hip/hip_runtime.h>
#include <stdint.h>

#define NN 50000
#define NE 800000

typedef short bf8_t __attribute__((ext_vector_type(8)));
typedef float f32x4 __attribute__((ext_vector_type(4)));

__device__ __forceinline__ float silu_f(float v) { return v / (1.0f + __expf(-v)); }

__device__ __forceinline__ unsigned int pack2bf(float a, float b) {
    unsigned int ua = __float_as_uint(a), ub = __float_as_uint(b);
    ua = (ua + 0x7fffu + ((ua >> 16) & 1u)) >> 16;
    ub = (ub + 0x7fffu + ((ub >> 16) & 1u)) >> 16;
    return ua | (ub << 16);
}

union U4B { uint4 u; bf8_t b; };
__device__ __forceinline__ bf8_t as_bf8(uint4 u) { U4B x; x.u = u; return x.b; }

// ---------------------------------------------------------------------------
// prep: x f32 -> bf16
// ---------------------------------------------------------------------------
__global__ __launch_bounds__(256) void prep_x(const float* __restrict__ x,
                                              unsigned short* __restrict__ xbf) {
    size_t i = (size_t)blockIdx.x * 256 + threadIdx.x;
    const float4* s = (const float4*)(x + i * 8);
    float4 v0 = s[0], v1 = s[1];
    uint4 o;
    o.x = pack2bf(v0.x, v0.y); o.y = pack2bf(v0.z, v0.w);
    o.z = pack2bf(v1.x, v1.y); o.w = pack2bf(v1.z, v1.w);
    *(uint4*)(xbf + i * 8) = o;
}

// ---------------------------------------------------------------------------
// prep: weight fragments in MFMA A-operand order (W^T), bf16.
// frag f = s*8 + mf: lane holds W[k = s*32 + (lane>>4)*8 + i][col = mf*16 + (lane&15)]
// b<64: We1 | 64..95: We2 | 96..159: Wn1 | 160..191: Wn2
// ---------------------------------------------------------------------------
__global__ __launch_bounds__(64) void prep_w(const float* __restrict__ We1,
                                             const float* __restrict__ We2,
                                             const float* __restrict__ Wn1,
                                             const float* __restrict__ Wn2,
                                             unsigned short* __restrict__ wf1,
                                             unsigned short* __restrict__ wf2,
                                             unsigned short* __restrict__ wfn1,
                                             unsigned short* __restrict__ wfn2) {
    int b = blockIdx.x, lane = threadIdx.x;
    int q = lane >> 4, c = lane & 15;
    const float* W; unsigned short* dst; int f;
    if (b < 64)       { W = We1; f = b;       dst = wf1  + (size_t)f * 512; }
    else if (b < 96)  { W = We2; f = b - 96 + 32;  f = b - 64;  dst = wf2  + (size_t)f * 512; }
    else if (b < 160) { W = Wn1; f = b - 96;  dst = wfn1 + (size_t)f * 512; }
    else              { W = Wn2; f = b - 160; dst = wfn2 + (size_t)f * 512; }
    int s = f >> 3, mf = f & 7;
    int k0 = s * 32 + q * 8, col = mf * 16 + c;
    float v[8];
    #pragma unroll
    for (int i = 0; i < 8; ++i) v[i] = W[(size_t)(k0 + i) * 128 + col];
    uint4 o;
    o.x = pack2bf(v[0], v[1]); o.y = pack2bf(v[2], v[3]);
    o.z = pack2bf(v[4], v[5]); o.w = pack2bf(v[6], v[7]);
    *(uint4*)(dst + lane * 8) = o;
}

// ---------------------------------------------------------------------------
// CSR build
// ---------------------------------------------------------------------------
__global__ __launch_bounds__(256) void egnn_hist(const int* __restrict__ ei,
                                                 int* __restrict__ cnt) {
    int e = blockIdx.x * 256 + threadIdx.x;
    if (e < NE) atomicAdd(&cnt[ei[e]], 1);
}

__global__ __launch_bounds__(1024) void egnn_scan(const int* __restrict__ cnt,
                                                  int* __restrict__ off,
                                                  int* __restrict__ cur) {
    __shared__ int part[1024];
    const int t = threadIdx.x;
    const int CH = (NN + 1023) / 1024;
    int lo = t * CH, hi = lo + CH; if (hi > NN) hi = NN; if (lo > NN) lo = NN;
    int s = 0;
    for (int i = lo; i < hi; ++i) s += cnt[i];
    part[t] = s;
    __syncthreads();
    for (int d = 1; d < 1024; d <<= 1) {
        int v = (t >= d) ? part[t - d] : 0;
        __syncthreads();
        part[t] += v;
        __syncthreads();
    }
    int base = (t == 0) ? 0 : part[t - 1];
    for (int i = lo; i < hi; ++i) { off[i] = base; cur[i] = base; base += cnt[i]; }
    if (t == 1023) off[NN] = NE;
}

__global__ __launch_bounds__(256) void egnn_scatter(const int* __restrict__ ei,
                                                    int* __restrict__ cur,
                                                    int* __restrict__ elist) {
    int e = blockIdx.x * 256 + threadIdx.x;
    if (e < NE) { int p = atomicAdd(&cur[ei[e]], 1); elist[p] = e; }
}

// ---------------------------------------------------------------------------
// Edge MFMA kernel, CSR-slot order. Block = 128 slots, 512 threads, 8 waves
// (P=4 col-quarters x Q=2 slot-halves). Weights read directly from global
// frag buffers (L2-resident). m/trans written at slot index (sequential).
// w_ij reduced in-block (shfl + LDS wdot), trans written here.
// ---------------------------------------------------------------------------
__global__ __launch_bounds__(512, 4) void egnn_edge_mfma(
    const unsigned short* __restrict__ xbf, const float* __restrict__ pos,
    const unsigned short* __restrict__ wf1, const unsigned short* __restrict__ wf2,
    const float* __restrict__ We1, const float* __restrict__ be1,
    const float* __restrict__ be2, const float* __restrict__ Wc,
    const float* __restrict__ bc,
    const int* __restrict__ ei, const int* __restrict__ elist,
    unsigned short* __restrict__ m_out, float* __restrict__ trans)
{
    __shared__ unsigned short Hs[128 * 136];   // 34.8 KB
    __shared__ int rows_s[128], cols_s[128];
    __shared__ float rij_s[128][3];
    __shared__ float dij_s[128];
    __shared__ float wdot[128];

    const int tid = threadIdx.x;
    const int e0 = blockIdx.x * 128;

    if (tid < 128) {
        int eid = elist[e0 + tid];
        int r = ei[eid], c = ei[NE + eid];
        rows_s[tid] = r; cols_s[tid] = c;
        float d = 0.f;
        #pragma unroll
        for (int k = 0; k < 3; ++k) {
            float rv = pos[r * 3 + k] - pos[c * 3 + k];
            rij_s[tid][k] = rv; d += rv * rv;
        }
        dij_s[tid] = d;
        wdot[tid] = 0.f;
    }
    __syncthreads();

    const int w = tid >> 6, lane = tid & 63;
    const int P = w & 3, Q = w >> 2;
    const int q = lane >> 4, e16 = lane & 15;
    const int oc_q = P * 32 + q * 4;

    int ridx[4], cidx[4], eloc[4];
    #pragma unroll
    for (int t = 0; t < 4; ++t) {
        int el = Q * 64 + t * 16 + e16; eloc[t] = el;
        ridx[t] = rows_s[el]; cidx[t] = cols_s[el];
    }

    // ---- layer 1: K=256 MFMA; dij rank-1 + bias as f32 fixup ----
    f32x4 acc[2][4];
    #pragma unroll
    for (int M = 0; M < 2; ++M) {
        float4 bi = *(const float4*)(be1 + oc_q + M * 16);
        #pragma unroll
        for (int t = 0; t < 4; ++t) { acc[M][t][0] = bi.x; acc[M][t][1] = bi.y; acc[M][t][2] = bi.z; acc[M][t][3] = bi.w; }
    }

    #pragma unroll
    for (int s = 0; s < 8; ++s) {
        bf8_t bfr[4];
        #pragma unroll
        for (int t = 0; t < 4; ++t) {
            int node = (s < 4) ? ridx[t] : cidx[t];
            bfr[t] = as_bf8(*(const uint4*)(xbf + (size_t)node * 128 + (s & 3) * 32 + q * 8));
        }
        #pragma unroll
        for (int M = 0; M < 2; ++M) {
            bf8_t af = as_bf8(*(const uint4*)(wf1 + (size_t)(s * 8 + P * 2 + M) * 512 + lane * 8));
            #pragma unroll
            for (int t = 0; t < 4; ++t)
                acc[M][t] = __builtin_amdgcn_mfma_f32_16x16x32_bf16(af, bfr[t], acc[M][t], 0, 0, 0);
        }
    }

    #pragma unroll
    for (int M = 0; M < 2; ++M) {
        float4 w256 = *(const float4*)(We1 + (size_t)256 * 128 + oc_q + M * 16);
        #pragma unroll
        for (int t = 0; t < 4; ++t) {
            float d = dij_s[eloc[t]];
            float v0 = silu_f(acc[M][t][0] + d * w256.x);
            float v1 = silu_f(acc[M][t][1] + d * w256.y);
            float v2 = silu_f(acc[M][t][2] + d * w256.z);
            float v3 = silu_f(acc[M][t][3] + d * w256.w);
            uint2 pk; pk.x = pack2bf(v0, v1); pk.y = pack2bf(v2, v3);
            *(uint2*)(Hs + (size_t)eloc[t] * 136 + oc_q + M * 16) = pk;
        }
    }
    __syncthreads();

    // ---- layer 2: K=128 ----
    f32x4 acc2[2][4];
    #pragma unroll
    for (int M = 0; M < 2; ++M) {
        float4 bi = *(const float4*)(be2 + oc_q + M * 16);
        #pragma unroll
        for (int t = 0; t < 4; ++t) { acc2[M][t][0] = bi.x; acc2[M][t][1] = bi.y; acc2[M][t][2] = bi.z; acc2[M][t][3] = bi.w; }
    }

    #pragma unroll
    for (int s = 0; s < 4; ++s) {
        bf8_t bfr[4];
        #pragma unroll
        for (int t = 0; t < 4; ++t)
            bfr[t] = as_bf8(*(const uint4*)(Hs + (size_t)eloc[t] * 136 + s * 32 + q * 8));
        #pragma unroll
        for (int M = 0; M < 2; ++M) {
            bf8_t af = as_bf8(*(const uint4*)(wf2 + (size_t)(s * 8 + P * 2 + M) * 512 + lane * 8));
            #pragma unroll
            for (int t = 0; t < 4; ++t)
                acc2[M][t] = __builtin_amdgcn_mfma_f32_16x16x32_bf16(af, bfr[t], acc2[M][t], 0, 0, 0);
        }
    }

    // ---- epilogue: m = silu(.), store at slot (sequential); wdot partials ----
    float4 wcA = *(const float4*)(Wc + oc_q);
    float4 wcB = *(const float4*)(Wc + oc_q + 16);
    float part[4];
    #pragma unroll
    for (int t = 0; t < 4; ++t) part[t] = 0.f;

    #pragma unroll
    for (int M = 0; M < 2; ++M) {
        float4 wc = (M == 0) ? wcA : wcB;
        #pragma unroll
        for (int t = 0; t < 4; ++t) {
            float v0 = silu_f(acc2[M][t][0]);
            float v1 = silu_f(acc2[M][t][1]);
            float v2 = silu_f(acc2[M][t][2]);
            float v3 = silu_f(acc2[M][t][3]);
            part[t] += v0 * wc.x + v1 * wc.y + v2 * wc.z + v3 * wc.w;
            uint2 pk; pk.x = pack2bf(v0, v1); pk.y = pack2bf(v2, v3);
            *(uint2*)(m_out + (size_t)(e0 + eloc[t]) * 128 + oc_q + M * 16) = pk;
        }
    }
    #pragma unroll
    for (int t = 0; t < 4; ++t) {
        float p = part[t];
        p += __shfl_xor(p, 16);
        p += __shfl_xor(p, 32);
        if (q == 0) atomicAdd(&wdot[eloc[t]], p);
    }
    __syncthreads();

    if (tid < 128) {
        float wgt = silu_f(wdot[tid] + bc[0]);
        size_t slot = (size_t)(e0 + tid);
        trans[slot * 3 + 0] = rij_s[tid][0] * wgt;
        trans[slot * 3 + 1] = rij_s[tid][1] * wgt;
        trans[slot * 3 + 2] = rij_s[tid][2] * wgt;
    }
}

// ---------------------------------------------------------------------------
// Gather: one wave per node; m and trans are CSR-ordered -> pure streaming.
// Writes agg as bf16 and pos_new directly into out.
// ---------------------------------------------------------------------------
__global__ __launch_bounds__(256) void egnn_gather(
    const unsigned short* __restrict__ m, const float* __restrict__ trans,
    const int* __restrict__ off, const float* __restrict__ pos,
    unsigned short* __restrict__ aggbf, float* __restrict__ out)
{
    int n = (blockIdx.x * 256 + threadIdx.x) >> 6;
    int lane = threadIdx.x & 63;
    const unsigned int* m32 = (const unsigned int*)m;
    int s = off[n], e_end = off[n + 1];
    float a0 = 0.f, a1 = 0.f, td = 0.f;
    for (int i = s; i < e_end; ++i) {
        unsigned int u = m32[(size_t)i * 64 + lane];
        a0 += __uint_as_float(u << 16);
        a1 += __uint_as_float(u & 0xffff0000u);
        if (lane < 3) td += trans[(size_t)i * 3 + lane];
    }
    aggbf[(size_t)n * 64 * 2 + lane * 2]     = (unsigned short)(pack2bf(a0, a1) & 0xffffu);
    aggbf[(size_t)n * 64 * 2 + lane * 2 + 1] = (unsigned short)(pack2bf(a0, a1) >> 16);
    if (lane < 3)
        out[(size_t)NN * 128 + (size_t)n * 3 + lane] =
            pos[(size_t)n * 3 + lane] + 0.01f * td;
}

// ---------------------------------------------------------------------------
// Node MFMA kernel: x_new = silu([x|agg] @ Wn1 + bn1) @ Wn2 + bn2
// Same swapped-GEMM structure; node rows contiguous (no gather).
// ---------------------------------------------------------------------------
__global__ __launch_bounds__(512, 4) void egnn_node_mfma(
    const unsigned short* __restrict__ xbf, const unsigned short* __restrict__ aggbf,
    const unsigned short* __restrict__ wfn1, const unsigned short* __restrict__ wfn2,
    const float* __restrict__ bn1, const float* __restrict__ bn2,
    float* __restrict__ out)
{
    __shared__ unsigned short Hs[128 * 136];

    const int tid = threadIdx.x;
    const int n0 = blockIdx.x * 128;
    const int w = tid >> 6, lane = tid & 63;
    const int P = w & 3, Q = w >> 2;
    const int q = lane >> 4, e16 = lane & 15;
    const int oc_q = P * 32 + q * 4;

    int nloc[4], nclamp[4];
    #pragma unroll
    for (int t = 0; t < 4; ++t) {
        int nl = Q * 64 + t * 16 + e16; nloc[t] = nl;
        int node = n0 + nl; nclamp[t] = (node >= NN) ? NN - 1 : node;
    }

    f32x4 acc[2][4];
    #pragma unroll
    for (int M = 0; M < 2; ++M) {
        float4 bi = *(const float4*)(bn1 + oc_q + M * 16);
        #pragma unroll
        for (int t = 0; t < 4; ++t) { acc[M][t][0] = bi.x; acc[M][t][1] = bi.y; acc[M][t][2] = bi.z; acc[M][t][3] = bi.w; }
    }

    #pragma unroll
    for (int s = 0; s < 8; ++s) {
        bf8_t bfr[4];
        #pragma unroll
        for (int t = 0; t < 4; ++t) {
            const unsigned short* base = (s < 4) ? xbf : aggbf;
            bfr[t] = as_bf8(*(const uint4*)(base + (size_t)nclamp[t] * 128 + (s & 3) * 32 + q * 8));
        }
        #pragma unroll
        for (int M = 0; M < 2; ++M) {
            bf8_t af = as_bf8(*(const uint4*)(wfn1 + (size_t)(s * 8 + P * 2 + M) * 512 + lane * 8));
            #pragma unroll
            for (int t = 0; t < 4; ++t)
                acc[M][t] = __builtin_amdgcn_mfma_f32_16x16x32_bf16(af, bfr[t], acc[M][t], 0, 0, 0);
        }
    }

    #pragma unroll
    for (int M = 0; M < 2; ++M) {
        #pragma unroll
        for (int t = 0; t < 4; ++t) {
            float v0 = silu_f(acc[M][t][0]);
            float v1 = silu_f(acc[M][t][1]);
            float v2 = silu_f(acc[M][t][2]);
            float v3 = silu_f(acc[M][t][3]);
            uint2 pk; pk.x = pack2bf(v0, v1); pk.y = pack2bf(v2, v3);
            *(uint2*)(Hs + (size_t)nloc[t] * 136 + oc_q + M * 16) = pk;
        }
    }
    __syncthreads();

    f32x4 acc2[2][4];
    #pragma unroll
    for (int M = 0; M < 2; ++M) {
        float4 bi = *(const float4*)(bn2 + oc_q + M * 16);
        #pragma unroll
        for (int t = 0; t < 4; ++t) { acc2[M][t][0] = bi.x; acc2[M][t][1] = bi.y; acc2[M][t][2] = bi.z; acc2[M][t][3] = bi.w; }
    }

    #pragma unroll
    for (int s = 0; s < 4; ++s) {
        bf8_t bfr[4];
        #pragma unroll
        for (int t = 0; t < 4; ++t)
            bfr[t] = as_bf8(*(const uint4*)(Hs + (size_t)nloc[t] * 136 + s * 32 + q * 8));
        #pragma unroll
        for (int M = 0; M < 2; ++M) {
            bf8_t af = as_bf8(*(const uint4*)(wfn2 + (size_t)(s * 8 + P * 2 + M) * 512 + lane * 8));
            #pragma unroll
            for (int t = 0; t < 4; ++t)
                acc2[M][t] = __builtin_amdgcn_mfma_f32_16x16x32_bf16(af, bfr[t], acc2[M][t], 0, 0, 0);
        }
    }

    #pragma unroll
    for (int M = 0; M < 2; ++M) {
        #pragma unroll
        for (int t = 0; t < 4; ++t) {
            int node = n0 + nloc[t];
            if (node < NN) {
                float4 v; v.x = acc2[M][t][0]; v.y = acc2[M][t][1]; v.z = acc2[M][t][2]; v.w = acc2[M][t][3];
                *(float4*)(out + (size_t)node * 128 + oc_q + M * 16) = v;
            }
        }
    }
}

extern "C" void kernel_launch(void* const* d_in, const int* in_sizes, int n_in,
                              void* d_out, int out_size, void* d_ws, size_t ws_size,
                              hipStream_t stream)
{
    const float* x   = (const float*)d_in[0];
    const float* pos = (const float*)d_in[1];
    const float* We1 = (const float*)d_in[2];
    const float* be1 = (const float*)d_in[3];
    const float* We2 = (const float*)d_in[4];
    const float* be2 = (const float*)d_in[5];
    const float* Wn1 = (const float*)d_in[6];
    const float* bn1 = (const float*)d_in[7];
    const float* Wn2 = (const float*)d_in[8];
    const float* bn2 = (const float*)d_in[9];
    const float* Wc  = (const float*)d_in[10];
    const float* bc  = (const float*)d_in[11];
    const int*   ei  = (const int*)d_in[12];
    float* out = (float*)d_out;

    // ws layout (~244.0 MB; proven ws >= 244.4 MB in R2)
    char* p = (char*)d_ws;
    unsigned short* m = (unsigned short*)p;    p += (size_t)NE * 128 * 2;   // 204.8 MB (CSR-slot order)
    float* trans = (float*)p;                  p += (size_t)NE * 3 * 4;     //   9.6 MB (CSR-slot order)
    unsigned short* xbf = (unsigned short*)p;  p += (size_t)NN * 128 * 2;   //  12.8 MB
    unsigned short* aggbf = (unsigned short*)p; p += (size_t)NN * 128 * 2;  //  12.8 MB
    unsigned short* wf1  = (unsigned short*)p; p += 65536;
    unsigned short* wf2  = (unsigned short*)p; p += 32768;
    unsigned short* wfn1 = (unsigned short*)p; p += 65536;
    unsigned short* wfn2 = (unsigned short*)p; p += 32768;
    int* cnt   = (int*)p;                      p += (size_t)NN * 4;
    int* off   = (int*)p;                      p += (size_t)(NN + 1) * 4 + 12;
    int* cur   = (int*)p;                      p += (size_t)NN * 4;
    int* elist = (int*)p;

    hipMemsetAsync(cnt, 0, (size_t)NN * 4, stream);
    prep_x<<<3125, 256, 0, stream>>>(x, xbf);
    prep_w<<<192, 64, 0, stream>>>(We1, We2, Wn1, Wn2, wf1, wf2, wfn1, wfn2);
    egnn_hist<<<NE / 256, 256, 0, stream>>>(ei, cnt);
    egnn_scan<<<1, 1024, 0, stream>>>(cnt, off, cur);
    egnn_scatter<<<NE / 256, 256, 0, stream>>>(ei, cur, elist);
    egnn_edge_mfma<<<NE / 128, 512, 0, stream>>>(xbf, pos, wf1, wf2, We1, be1, be2,
                                                 Wc, bc, ei, elist, m, trans);
    egnn_gather<<<(NN * 64) / 256, 256, 0, stream>>>(m, trans, off, pos, aggbf, out);
    egnn_node_mfma<<<(NN + 127) / 128, 512, 0, stream>>>(xbf, aggbf, wfn1, wfn2, bn1, bn2, out);
}